// Round 6
// baseline (222.778 us; speedup 1.0000x reference)
//
#include <hip/hip_runtime.h>
#include <hip/hip_bf16.h>

// AttentionHeadRankFour: B=8, X=8, S=1024, D_IN=512, D_OUT=64
// out = softmax_causal( (Xq Wq)(Xk Wk)^T / sqrt(S) ) (Xv Wv)
//
// Pass 0: wprep converts W (fp32) -> bf16 fragment-ordered (q_w pre-scaled 1/32).
// Pass 1: proj v6 — many small blocks (BM=64, 256 thr), A via 16 KB LDS double
//         buffer (2-chunk-ahead register staging), W-frags read from L2 directly.
// Pass 2: flash attention, bf16 MFMA, online softmax.

typedef short  short8 __attribute__((ext_vector_type(8)));
typedef float  f32x4  __attribute__((ext_vector_type(4)));

#define DIN   512
#define DOUT  64
#define SEQ   1024
#define NROWS 65536   // 8*8*1024

__device__ __forceinline__ unsigned short f2bf(float f) {
    unsigned int u = __float_as_uint(f);
    u += 0x7FFF + ((u >> 16) & 1);   // RNE
    return (unsigned short)(u >> 16);
}

// ---------------------------------------------------------------------------
// Weight prep: grid (16,3), 256 thr. Wfrag[mode][kk][nt][lane][8] bf16,
// element = W[kk*32 + lg*8 + j][nt*16 + lr]; mode 2 pre-scaled by 1/32.
// ---------------------------------------------------------------------------
__global__ __launch_bounds__(256)
void wprep_kernel(const float* __restrict__ k_w, const float* __restrict__ v_w,
                  const float* __restrict__ q_w, unsigned short* __restrict__ Wfrag)
{
    const int mode = blockIdx.y;
    const float* w = (mode == 0) ? k_w : (mode == 1) ? v_w : q_w;
    const float sc = (mode == 2) ? 0.03125f : 1.0f;
    unsigned short* outp = Wfrag + (size_t)mode * 32768;

    const int s  = blockIdx.x * 256 + threadIdx.x;   // (kk,nt,lane) slot
    const int l  = s & 63;
    const int nt = (s >> 6) & 3;
    const int kk = s >> 8;
    const int lr = l & 15, lg = l >> 4;
    short8 frag;
    #pragma unroll
    for (int j = 0; j < 8; ++j)
        frag[j] = (short)f2bf(w[(kk * 32 + lg * 8 + j) * 64 + nt * 16 + lr] * sc);
    *(short8*)&outp[(size_t)s * 8] = frag;
}

// ---------------------------------------------------------------------------
// proj v6. Grid (1024, 3), 256 thr = 4 waves, __launch_bounds__(256,4).
// Block owns 64 rows x K=512 in 8 chunks of 64 cols. Per chunk: coalesced
// fp32 loads (2 chunks ahead, reg sets rA/rB) -> f2bf -> XOR-swizzled 8 KB
// LDS buffer (x2). Wave w computes rows [w*16,+16) x all 64 out-cols;
// B-operands (W frags) loaded directly from global (L2-resident, 192 KB).
// ---------------------------------------------------------------------------
__global__ __launch_bounds__(256, 4)
void proj_kernel(const float* __restrict__ k_in, const float* __restrict__ v_in,
                 const float* __restrict__ q_in,
                 const unsigned short* __restrict__ Wfrag,
                 unsigned short* __restrict__ Kb, unsigned short* __restrict__ Vt,
                 unsigned short* __restrict__ Qb)
{
    const int mode = blockIdx.y;
    const float* in = (mode == 0) ? k_in : (mode == 1) ? v_in : q_in;
    const unsigned short* wf = Wfrag + (size_t)mode * 32768;

    __shared__ __align__(16) unsigned short Alds[2][4096];   // 2 x 8 KB bf16 [64][64]

    const int tid = threadIdx.x;
    const int wid = tid >> 6;
    const int l   = tid & 63;
    const int lr  = l & 15;
    const int lg  = l >> 4;
    const int r0  = blockIdx.x * 64;

    // Staging: thread t -> row t>>2, col base (t&3)*16 (+i*4), contiguous 64B.
    const int srow  = tid >> 2;
    const int scol  = (tid & 3) * 16;
    const float* sbase = in + (size_t)(r0 + srow) * DIN + scol;
    const int swbase = (srow * 128 + scol * 2);      // byte offset in LDS row
    const int sswz   = (srow & 7) << 4;

    float4 rS[2][4];

    #define LOADC(set, c)                                                      \
        { _Pragma("unroll")                                                    \
          for (int i = 0; i < 4; ++i)                                          \
              rS[set][i] = *(const float4*)(sbase + (c) * 64 + i * 4); }

    #define WRITEC(buf, set)                                                   \
        { _Pragma("unroll")                                                    \
          for (int i = 0; i < 4; ++i) {                                        \
              ushort4 pk;                                                      \
              pk.x = f2bf(rS[set][i].x); pk.y = f2bf(rS[set][i].y);            \
              pk.z = f2bf(rS[set][i].z); pk.w = f2bf(rS[set][i].w);            \
              *(ushort4*)((char*)&Alds[buf][0] +                               \
                          ((swbase + i * 8) ^ sswz)) = pk;                     \
          } }

    // Fragment read geometry: wave wid computes rows wid*16 + lr.
    const int arow  = wid * 16 + lr;
    const int abase = arow * 128 + lg * 16;          // + kk*64, byte offset
    const int aswz  = (arow & 7) << 4;

    f32x4 acc[4];
    #pragma unroll
    for (int nt = 0; nt < 4; ++nt)
        #pragma unroll
        for (int i = 0; i < 4; ++i) acc[nt][i] = 0.f;

    #define COMPUTEC(buf, c)                                                   \
        { _Pragma("unroll")                                                    \
          for (int k = 0; k < 2; ++k) {                                        \
              const short8 af = *(const short8*)((const char*)&Alds[buf][0] +  \
                                  ((abase + k * 64) ^ aswz));                  \
              const int kkg = (c) * 2 + k;                                     \
              _Pragma("unroll")                                                \
              for (int nt = 0; nt < 4; ++nt) {                                 \
                  const short8 bfr = *(const short8*)&wf[((kkg * 4 + nt) * 64 + l) * 8]; \
                  acc[nt] = __builtin_amdgcn_mfma_f32_16x16x32_bf16(af, bfr, acc[nt], 0, 0, 0); \
              }                                                                \
          } }

    // Prologue: chunks 0,1 into reg sets; write 0; barrier.
    LOADC(0, 0);
    LOADC(1, 1);
    WRITEC(0, 0);
    __syncthreads();

    #pragma unroll
    for (int c = 0; c < 8; ++c) {
        if (c < 6) LOADC(c & 1, c + 2);          // chunk c+2 -> set (c+2)&1 == c&1
        if (c < 7) WRITEC((c + 1) & 1, (c + 1) & 1);
        COMPUTEC(c & 1, c);
        if (c < 7) __syncthreads();
    }

    // Epilogue. C frag: col = lr, row = lg*4 + i within wave tile (base wid*16).
    if (mode == 1) {
        const int grow = r0 + wid * 16 + lg * 4;
        const int bx = grow >> 10, s = grow & 1023;
        #pragma unroll
        for (int nt = 0; nt < 4; ++nt) {
            ushort4 pk;
            pk.x = f2bf(acc[nt][0]); pk.y = f2bf(acc[nt][1]);
            pk.z = f2bf(acc[nt][2]); pk.w = f2bf(acc[nt][3]);
            *(ushort4*)&Vt[(size_t)bx * 65536 + (size_t)(nt * 16 + lr) * 1024 + s] = pk;
        }
    } else {
        unsigned short* outp = (mode == 0) ? Kb : Qb;
        const int rbase = r0 + wid * 16 + lg * 4;
        #pragma unroll
        for (int nt = 0; nt < 4; ++nt)
            #pragma unroll
            for (int i = 0; i < 4; ++i)
                outp[(size_t)(rbase + i) * 64 + nt * 16 + lr] = f2bf(acc[nt][i]);
    }
    #undef LOADC
    #undef WRITEC
    #undef COMPUTEC
}

// ---------------------------------------------------------------------------
// Flash attention, causal. Grid: (16 q-blocks, 64 bx heads). 256 thr = 4 waves.
// Wave w owns q rows [qblk*64 + w*16, +16). KB=64 keys per chunk.
// ---------------------------------------------------------------------------
__global__ __launch_bounds__(256)
void attn_kernel(const unsigned short* __restrict__ Qb,
                 const unsigned short* __restrict__ Kb,
                 const unsigned short* __restrict__ Vt,
                 float* __restrict__ out)
{
    __shared__ __align__(16) unsigned short Plds[4][16][72];  // per-wave P tile, padded

    const int tid  = threadIdx.x;
    const int wid  = tid >> 6;
    const int l    = tid & 63;
    const int lr   = l & 15;
    const int lg   = l >> 4;
    const int qblk = 15 - (int)blockIdx.x;       // big blocks first
    const int bx   = blockIdx.y;
    const int qw0  = qblk * 64 + wid * 16;

    const unsigned short* Qp = Qb + (size_t)bx * 65536;
    const unsigned short* Kp = Kb + (size_t)bx * 65536;
    const unsigned short* Vp = Vt + (size_t)bx * 65536;   // [d][s]

    const short8 qa0 = *(const short8*)&Qp[(size_t)(qw0 + lr) * 64 + lg * 8];
    const short8 qa1 = *(const short8*)&Qp[(size_t)(qw0 + lr) * 64 + 32 + lg * 8];

    float m[4], lsum[4];
    f32x4 acc[4];
    #pragma unroll
    for (int i = 0; i < 4; ++i) { m[i] = -INFINITY; lsum[i] = 0.f; }
    #pragma unroll
    for (int dt = 0; dt < 4; ++dt)
        #pragma unroll
        for (int i = 0; i < 4; ++i) acc[dt][i] = 0.f;

    const int qrow = qw0 + lg * 4;   // + i

    for (int kb = 0; kb <= qw0; kb += 64) {
        // ---- scores: 4 tiles of 16 keys ----
        f32x4 s[4];
        #pragma unroll
        for (int kt = 0; kt < 4; ++kt) {
            const int kbase = kb + kt * 16;
            if (kbase <= qw0 + 15) {           // wave-uniform
                const short8 k0 = *(const short8*)&Kp[(size_t)(kbase + lr) * 64 + lg * 8];
                const short8 k1 = *(const short8*)&Kp[(size_t)(kbase + lr) * 64 + 32 + lg * 8];
                f32x4 t;
                #pragma unroll
                for (int i = 0; i < 4; ++i) t[i] = 0.f;
                t = __builtin_amdgcn_mfma_f32_16x16x32_bf16(qa0, k0, t, 0, 0, 0);
                t = __builtin_amdgcn_mfma_f32_16x16x32_bf16(qa1, k1, t, 0, 0, 0);
                const int kcol = kbase + lr;
                #pragma unroll
                for (int i = 0; i < 4; ++i)
                    s[kt][i] = (kcol <= qrow + i) ? t[i] : -INFINITY;
            } else {
                #pragma unroll
                for (int i = 0; i < 4; ++i) s[kt][i] = -INFINITY;
            }
        }
        // ---- online softmax ----
        float tm[4];
        #pragma unroll
        for (int i = 0; i < 4; ++i)
            tm[i] = fmaxf(fmaxf(s[0][i], s[1][i]), fmaxf(s[2][i], s[3][i]));
        #pragma unroll
        for (int d = 1; d < 16; d <<= 1)
            #pragma unroll
            for (int i = 0; i < 4; ++i)
                tm[i] = fmaxf(tm[i], __shfl_xor(tm[i], d));

        float rs[4], ps[4];
        #pragma unroll
        for (int i = 0; i < 4; ++i) {
            const float mn = fmaxf(m[i], tm[i]);
            rs[i] = __expf(m[i] - mn);
            m[i] = mn;
            ps[i] = 0.f;
        }
        #pragma unroll
        for (int kt = 0; kt < 4; ++kt)
            #pragma unroll
            for (int i = 0; i < 4; ++i) {
                const float p = __expf(s[kt][i] - m[i]);   // masked -> 0
                ps[i] += p;
                Plds[wid][lg * 4 + i][kt * 16 + lr] = f2bf(p);
            }
        #pragma unroll
        for (int d = 1; d < 16; d <<= 1)
            #pragma unroll
            for (int i = 0; i < 4; ++i) ps[i] += __shfl_xor(ps[i], d);
        #pragma unroll
        for (int i = 0; i < 4; ++i) lsum[i] = lsum[i] * rs[i] + ps[i];
        #pragma unroll
        for (int dt = 0; dt < 4; ++dt)
            #pragma unroll
            for (int i = 0; i < 4; ++i) acc[dt][i] *= rs[i];

        // wave-private LDS write -> read (same wave); drain LDS then re-read
        asm volatile("s_waitcnt lgkmcnt(0)" ::: "memory");
        __builtin_amdgcn_sched_barrier(0);

        // ---- PV ----
        const int cmax = (kb + 32 <= qw0 + 15) ? 2 : 1;
        for (int c = 0; c < cmax; ++c) {
            const short8 pa = *(const short8*)&Plds[wid][lr][c * 32 + lg * 8];
            #pragma unroll
            for (int dt = 0; dt < 4; ++dt) {
                const short8 vb = *(const short8*)&Vp[(size_t)(dt * 16 + lr) * 1024 + kb + c * 32 + lg * 8];
                acc[dt] = __builtin_amdgcn_mfma_f32_16x16x32_bf16(pa, vb, acc[dt], 0, 0, 0);
            }
        }
        asm volatile("s_waitcnt lgkmcnt(0)" ::: "memory");
    }

    // ---- epilogue ----
    float inv[4];
    #pragma unroll
    for (int i = 0; i < 4; ++i) inv[i] = 1.0f / lsum[i];
    const size_t orow = (size_t)bx * 1024 + qw0;
    #pragma unroll
    for (int dt = 0; dt < 4; ++dt)
        #pragma unroll
        for (int i = 0; i < 4; ++i)
            out[(orow + lg * 4 + i) * 64 + dt * 16 + lr] = acc[dt][i] * inv[i];
}

extern "C" void kernel_launch(void* const* d_in, const int* in_sizes, int n_in,
                              void* d_out, int out_size, void* d_ws, size_t ws_size,
                              hipStream_t stream) {
    const float* k_in = (const float*)d_in[0];
    const float* v_in = (const float*)d_in[1];
    const float* q_in = (const float*)d_in[2];
    const float* k_w  = (const float*)d_in[3];
    const float* v_w  = (const float*)d_in[4];
    const float* q_w  = (const float*)d_in[5];

    unsigned short* Kb    = (unsigned short*)d_ws;              // [65536][64] bf16
    unsigned short* Vt    = Kb + (size_t)NROWS * 64;            // [64][64][1024] bf16
    unsigned short* Qb    = Vt + (size_t)NROWS * 64;            // [65536][64] bf16 (scale in W)
    unsigned short* Wfrag = Qb + (size_t)NROWS * 64;            // 3 x 32768 bf16 fragments

    wprep_kernel<<<dim3(16, 3), 256, 0, stream>>>(k_w, v_w, q_w, Wfrag);
    proj_kernel<<<dim3(1024, 3), 256, 0, stream>>>(
        k_in, v_in, q_in, Wfrag, Kb, Vt, Qb);
    attn_kernel<<<dim3(16, 64), 256, 0, stream>>>(Qb, Kb, Vt, (float*)d_out);
}

// Round 7
// 211.986 us; speedup vs baseline: 1.0509x; 1.0509x over previous
//
#include <hip/hip_runtime.h>
#include <hip/hip_bf16.h>

// AttentionHeadRankFour: B=8, X=8, S=1024, D_IN=512, D_OUT=64
// out = softmax_causal( (Xq Wq)(Xk Wk)^T / sqrt(S) ) (Xv Wv)
//
// Pass 0: wprep converts W (fp32) -> bf16 fragment-ordered (q_w pre-scaled 1/32).
// Pass 1: proj v7 — per-wave async global_load_lds pipeline (width=16, counted
//         vmcnt, wave-private LDS double buffer, ZERO barriers), fp32 in LDS,
//         source-pre-swizzled so swizzled ds_read_b128 is conflict-free.
// Pass 2: flash attention, bf16 MFMA, online softmax.

typedef short  short8 __attribute__((ext_vector_type(8)));
typedef float  f32x4  __attribute__((ext_vector_type(4)));

#define DIN   512
#define DOUT  64
#define SEQ   1024
#define NROWS 65536   // 8*8*1024

__device__ __forceinline__ unsigned short f2bf(float f) {
    unsigned int u = __float_as_uint(f);
    u += 0x7FFF + ((u >> 16) & 1);   // RNE
    return (unsigned short)(u >> 16);
}

#define GLD_LDS16(gp, lp)                                                      \
    __builtin_amdgcn_global_load_lds(                                          \
        (const __attribute__((address_space(1))) unsigned int*)(gp),           \
        (__attribute__((address_space(3))) unsigned int*)(lp), 16, 0, 0)

// ---------------------------------------------------------------------------
// Weight prep: grid (16,3), 256 thr. Wfrag[mode][kk][nt][lane][8] bf16,
// element = W[kk*32 + lg*8 + j][nt*16 + lr]; mode 2 pre-scaled by 1/32.
// ---------------------------------------------------------------------------
__global__ __launch_bounds__(256)
void wprep_kernel(const float* __restrict__ k_w, const float* __restrict__ v_w,
                  const float* __restrict__ q_w, unsigned short* __restrict__ Wfrag)
{
    const int mode = blockIdx.y;
    const float* w = (mode == 0) ? k_w : (mode == 1) ? v_w : q_w;
    const float sc = (mode == 2) ? 0.03125f : 1.0f;
    unsigned short* outp = Wfrag + (size_t)mode * 32768;

    const int s  = blockIdx.x * 256 + threadIdx.x;   // (kk,nt,lane) slot
    const int l  = s & 63;
    const int nt = (s >> 6) & 3;
    const int kk = s >> 8;
    const int lr = l & 15, lg = l >> 4;
    short8 frag;
    #pragma unroll
    for (int j = 0; j < 8; ++j)
        frag[j] = (short)f2bf(w[(kk * 32 + lg * 8 + j) * 64 + nt * 16 + lr] * sc);
    *(short8*)&outp[(size_t)s * 8] = frag;
}

// ---------------------------------------------------------------------------
// proj v7. Grid (1024, 3), 256 thr = 4 waves. Wave w owns rows
// [blockIdx.x*64 + w*16, +16) x full K=512, in 8 chunks of 64 fp32.
// Staging: 4 x global_load_lds(16B) per chunk into wave-private LDS buffer
// (linear dest; global source pre-swizzled by ((row&7)<<4) so the swizzled
// ds_read_b128 fragment reads are bank-conflict-free). No __syncthreads.
// W-frag B-operands read from global (L2-resident) each chunk.
// ---------------------------------------------------------------------------
__global__ __launch_bounds__(256)
void proj_kernel(const float* __restrict__ k_in, const float* __restrict__ v_in,
                 const float* __restrict__ q_in,
                 const unsigned short* __restrict__ Wfrag,
                 unsigned short* __restrict__ Kb, unsigned short* __restrict__ Vt,
                 unsigned short* __restrict__ Qb)
{
    const int mode = blockIdx.y;
    const float* in = (mode == 0) ? k_in : (mode == 1) ? v_in : q_in;
    const unsigned short* wf = Wfrag + (size_t)mode * 32768;

    __shared__ __align__(16) float Alds[4][2][1024];   // [wave][dbuf][4 KB]

    const int tid = threadIdx.x;
    const int wid = tid >> 6;
    const int l   = tid & 63;
    const int lr  = l & 15;
    const int lg  = l >> 4;
    const int r0  = blockIdx.x * 64;

    // Per-lane pre-swizzled global source pointers for the 4 staging instrs.
    // Physical LDS offset of instr j, lane i: j*1024 + i*16 ->
    // row = j*4 + (i>>4), physcol = (i&15)*16; logical col = physcol ^ ((row&7)<<4).
    const char* gp[4];
    #pragma unroll
    for (int j = 0; j < 4; ++j) {
        const int rj = j * 4 + (l >> 4);
        gp[j] = (const char*)in + (size_t)(r0 + wid * 16 + rj) * 2048
                + (((l & 15) * 16) ^ ((rj & 7) << 4));
    }

    const int swz = (lr & 7) << 4;   // read-side swizzle for this lane's row

    f32x4 acc[4];
    #pragma unroll
    for (int nt = 0; nt < 4; ++nt)
        #pragma unroll
        for (int i = 0; i < 4; ++i) acc[nt][i] = 0.f;

    // Prologue: stage chunk 0 into buf 0.
    #pragma unroll
    for (int j = 0; j < 4; ++j)
        GLD_LDS16(gp[j] + 0 * 256, (char*)&Alds[wid][0][0] + j * 1024);

    #define PROJ_ITER(c, WAIT)                                                 \
    {                                                                          \
        /* W fragments for chunk c (L2) */                                     \
        short8 bfr[8];                                                         \
        _Pragma("unroll")                                                      \
        for (int q = 0; q < 8; ++q)                                            \
            bfr[q] = *(const short8*)&wf[((((c) * 2 + (q >> 2)) * 4 + (q & 3)) * 64 + l) * 8]; \
        /* stage chunk c+1 */                                                  \
        if ((c) < 7) {                                                         \
            _Pragma("unroll")                                                  \
            for (int j = 0; j < 4; ++j)                                        \
                GLD_LDS16(gp[j] + ((c) + 1) * 256,                             \
                          (char*)&Alds[wid][((c) + 1) & 1][0] + j * 1024);     \
        }                                                                      \
        asm volatile("s_waitcnt vmcnt(" #WAIT ")" ::: "memory");               \
        __builtin_amdgcn_sched_barrier(0);                                     \
        const char* bufb = (const char*)&Alds[wid][(c) & 1][0];                \
        _Pragma("unroll")                                                      \
        for (int kk = 0; kk < 2; ++kk) {                                       \
            const int colb = kk * 128 + lg * 32;                               \
            const float4 x0 = *(const float4*)(bufb + lr * 256 + ((colb)      ^ swz)); \
            const float4 x1 = *(const float4*)(bufb + lr * 256 + ((colb + 16) ^ swz)); \
            short8 af;                                                         \
            af[0] = (short)f2bf(x0.x); af[1] = (short)f2bf(x0.y);              \
            af[2] = (short)f2bf(x0.z); af[3] = (short)f2bf(x0.w);              \
            af[4] = (short)f2bf(x1.x); af[5] = (short)f2bf(x1.y);              \
            af[6] = (short)f2bf(x1.z); af[7] = (short)f2bf(x1.w);              \
            _Pragma("unroll")                                                  \
            for (int nt = 0; nt < 4; ++nt)                                     \
                acc[nt] = __builtin_amdgcn_mfma_f32_16x16x32_bf16(             \
                    af, bfr[kk * 4 + nt], acc[nt], 0, 0, 0);                   \
        }                                                                      \
    }

    PROJ_ITER(0, 4)
    PROJ_ITER(1, 4)
    PROJ_ITER(2, 4)
    PROJ_ITER(3, 4)
    PROJ_ITER(4, 4)
    PROJ_ITER(5, 4)
    PROJ_ITER(6, 4)
    PROJ_ITER(7, 0)
    #undef PROJ_ITER

    // Epilogue. C frag: col = lr, row = lg*4 + i within wave tile.
    if (mode == 1) {
        const int grow = r0 + wid * 16 + lg * 4;
        const int bx = grow >> 10, s = grow & 1023;
        #pragma unroll
        for (int nt = 0; nt < 4; ++nt) {
            ushort4 pk;
            pk.x = f2bf(acc[nt][0]); pk.y = f2bf(acc[nt][1]);
            pk.z = f2bf(acc[nt][2]); pk.w = f2bf(acc[nt][3]);
            *(ushort4*)&Vt[(size_t)bx * 65536 + (size_t)(nt * 16 + lr) * 1024 + s] = pk;
        }
    } else {
        unsigned short* outp = (mode == 0) ? Kb : Qb;
        const int rbase = r0 + wid * 16 + lg * 4;
        #pragma unroll
        for (int nt = 0; nt < 4; ++nt)
            #pragma unroll
            for (int i = 0; i < 4; ++i)
                outp[(size_t)(rbase + i) * 64 + nt * 16 + lr] = f2bf(acc[nt][i]);
    }
}

// ---------------------------------------------------------------------------
// Flash attention, causal. Grid: (16 q-blocks, 64 bx heads). 256 thr = 4 waves.
// Wave w owns q rows [qblk*64 + w*16, +16). KB=64 keys per chunk.
// ---------------------------------------------------------------------------
__global__ __launch_bounds__(256)
void attn_kernel(const unsigned short* __restrict__ Qb,
                 const unsigned short* __restrict__ Kb,
                 const unsigned short* __restrict__ Vt,
                 float* __restrict__ out)
{
    __shared__ __align__(16) unsigned short Plds[4][16][72];  // per-wave P tile, padded

    const int tid  = threadIdx.x;
    const int wid  = tid >> 6;
    const int l    = tid & 63;
    const int lr   = l & 15;
    const int lg   = l >> 4;
    const int qblk = 15 - (int)blockIdx.x;       // big blocks first
    const int bx   = blockIdx.y;
    const int qw0  = qblk * 64 + wid * 16;

    const unsigned short* Qp = Qb + (size_t)bx * 65536;
    const unsigned short* Kp = Kb + (size_t)bx * 65536;
    const unsigned short* Vp = Vt + (size_t)bx * 65536;   // [d][s]

    const short8 qa0 = *(const short8*)&Qp[(size_t)(qw0 + lr) * 64 + lg * 8];
    const short8 qa1 = *(const short8*)&Qp[(size_t)(qw0 + lr) * 64 + 32 + lg * 8];

    float m[4], lsum[4];
    f32x4 acc[4];
    #pragma unroll
    for (int i = 0; i < 4; ++i) { m[i] = -INFINITY; lsum[i] = 0.f; }
    #pragma unroll
    for (int dt = 0; dt < 4; ++dt)
        #pragma unroll
        for (int i = 0; i < 4; ++i) acc[dt][i] = 0.f;

    const int qrow = qw0 + lg * 4;   // + i

    for (int kb = 0; kb <= qw0; kb += 64) {
        // ---- scores: 4 tiles of 16 keys ----
        f32x4 s[4];
        #pragma unroll
        for (int kt = 0; kt < 4; ++kt) {
            const int kbase = kb + kt * 16;
            if (kbase <= qw0 + 15) {           // wave-uniform
                const short8 k0 = *(const short8*)&Kp[(size_t)(kbase + lr) * 64 + lg * 8];
                const short8 k1 = *(const short8*)&Kp[(size_t)(kbase + lr) * 64 + 32 + lg * 8];
                f32x4 t;
                #pragma unroll
                for (int i = 0; i < 4; ++i) t[i] = 0.f;
                t = __builtin_amdgcn_mfma_f32_16x16x32_bf16(qa0, k0, t, 0, 0, 0);
                t = __builtin_amdgcn_mfma_f32_16x16x32_bf16(qa1, k1, t, 0, 0, 0);
                const int kcol = kbase + lr;
                #pragma unroll
                for (int i = 0; i < 4; ++i)
                    s[kt][i] = (kcol <= qrow + i) ? t[i] : -INFINITY;
            } else {
                #pragma unroll
                for (int i = 0; i < 4; ++i) s[kt][i] = -INFINITY;
            }
        }
        // ---- online softmax ----
        float tm[4];
        #pragma unroll
        for (int i = 0; i < 4; ++i)
            tm[i] = fmaxf(fmaxf(s[0][i], s[1][i]), fmaxf(s[2][i], s[3][i]));
        #pragma unroll
        for (int d = 1; d < 16; d <<= 1)
            #pragma unroll
            for (int i = 0; i < 4; ++i)
                tm[i] = fmaxf(tm[i], __shfl_xor(tm[i], d));

        float rs[4], ps[4];
        #pragma unroll
        for (int i = 0; i < 4; ++i) {
            const float mn = fmaxf(m[i], tm[i]);
            rs[i] = __expf(m[i] - mn);
            m[i] = mn;
            ps[i] = 0.f;
        }
        #pragma unroll
        for (int kt = 0; kt < 4; ++kt)
            #pragma unroll
            for (int i = 0; i < 4; ++i) {
                const float p = __expf(s[kt][i] - m[i]);   // masked -> 0
                ps[i] += p;
                Plds[wid][lg * 4 + i][kt * 16 + lr] = f2bf(p);
            }
        #pragma unroll
        for (int d = 1; d < 16; d <<= 1)
            #pragma unroll
            for (int i = 0; i < 4; ++i) ps[i] += __shfl_xor(ps[i], d);
        #pragma unroll
        for (int i = 0; i < 4; ++i) lsum[i] = lsum[i] * rs[i] + ps[i];
        #pragma unroll
        for (int dt = 0; dt < 4; ++dt)
            #pragma unroll
            for (int i = 0; i < 4; ++i) acc[dt][i] *= rs[i];

        // wave-private LDS write -> read (same wave); drain LDS then re-read
        asm volatile("s_waitcnt lgkmcnt(0)" ::: "memory");
        __builtin_amdgcn_sched_barrier(0);

        // ---- PV ----
        const int cmax = (kb + 32 <= qw0 + 15) ? 2 : 1;
        for (int c = 0; c < cmax; ++c) {
            const short8 pa = *(const short8*)&Plds[wid][lr][c * 32 + lg * 8];
            #pragma unroll
            for (int dt = 0; dt < 4; ++dt) {
                const short8 vb = *(const short8*)&Vp[(size_t)(dt * 16 + lr) * 1024 + kb + c * 32 + lg * 8];
                acc[dt] = __builtin_amdgcn_mfma_f32_16x16x32_bf16(pa, vb, acc[dt], 0, 0, 0);
            }
        }
        asm volatile("s_waitcnt lgkmcnt(0)" ::: "memory");
    }

    // ---- epilogue ----
    float inv[4];
    #pragma unroll
    for (int i = 0; i < 4; ++i) inv[i] = 1.0f / lsum[i];
    const size_t orow = (size_t)bx * 1024 + qw0;
    #pragma unroll
    for (int dt = 0; dt < 4; ++dt)
        #pragma unroll
        for (int i = 0; i < 4; ++i)
            out[(orow + lg * 4 + i) * 64 + dt * 16 + lr] = acc[dt][i] * inv[i];
}

extern "C" void kernel_launch(void* const* d_in, const int* in_sizes, int n_in,
                              void* d_out, int out_size, void* d_ws, size_t ws_size,
                              hipStream_t stream) {
    const float* k_in = (const float*)d_in[0];
    const float* v_in = (const float*)d_in[1];
    const float* q_in = (const float*)d_in[2];
    const float* k_w  = (const float*)d_in[3];
    const float* v_w  = (const float*)d_in[4];
    const float* q_w  = (const float*)d_in[5];

    unsigned short* Kb    = (unsigned short*)d_ws;              // [65536][64] bf16
    unsigned short* Vt    = Kb + (size_t)NROWS * 64;            // [64][64][1024] bf16
    unsigned short* Qb    = Vt + (size_t)NROWS * 64;            // [65536][64] bf16 (scale in W)
    unsigned short* Wfrag = Qb + (size_t)NROWS * 64;            // 3 x 32768 bf16 fragments

    wprep_kernel<<<dim3(16, 3), 256, 0, stream>>>(k_w, v_w, q_w, Wfrag);
    proj_kernel<<<dim3(1024, 3), 256, 0, stream>>>(
        k_in, v_in, q_in, Wfrag, Kb, Vt, Qb);
    attn_kernel<<<dim3(16, 64), 256, 0, stream>>>(Qb, Kb, Vt, (float*)d_out);
}

// Round 9
// 199.537 us; speedup vs baseline: 1.1165x; 1.0624x over previous
//
#include <hip/hip_runtime.h>
#include <hip/hip_bf16.h>

// AttentionHeadRankFour: B=8, X=8, S=1024, D_IN=512, D_OUT=64
// out = softmax_causal( (Xq Wq)(Xk Wk)^T / sqrt(S) ) (Xv Wv)
//
// Pass 0: wprep -> bf16 fragment-ordered W (q_w pre-scaled by log2e/32).
// Pass 1: proj (r5 structure) + NON-TEMPORAL A loads (L3-bypass experiment).
// Pass 2: attn v2 — swapped QK^T (lane-local rows), log2-domain softmax,
//         packed P writes, hoisted V loads, setprio around MFMA.

typedef short  short8 __attribute__((ext_vector_type(8)));
typedef float  f32x4  __attribute__((ext_vector_type(4)));

#define DIN   512
#define DOUT  64
#define SEQ   1024
#define NROWS 65536   // 8*8*1024

__device__ __forceinline__ unsigned short f2bf(float f) {
    unsigned int u = __float_as_uint(f);
    u += 0x7FFF + ((u >> 16) & 1);   // RNE
    return (unsigned short)(u >> 16);
}

__device__ __forceinline__ unsigned short f2bf_rhu(float f) {   // round-half-up (cheap)
    return (unsigned short)((__float_as_uint(f) + 0x8000u) >> 16);
}

__device__ __forceinline__ float fast_exp2(float x) {
    float r;
    asm("v_exp_f32 %0, %1" : "=v"(r) : "v"(x));
    return r;
}

// ---------------------------------------------------------------------------
// Weight prep: grid (16,3), 256 thr. Wfrag[mode][kk][nt][lane][8] bf16,
// element = W[kk*32 + lg*8 + j][nt*16 + lr]; mode 2 pre-scaled by log2e/32
// (softmax runs in log2 domain).
// ---------------------------------------------------------------------------
__global__ __launch_bounds__(256)
void wprep_kernel(const float* __restrict__ k_w, const float* __restrict__ v_w,
                  const float* __restrict__ q_w, unsigned short* __restrict__ Wfrag)
{
    const int mode = blockIdx.y;
    const float* w = (mode == 0) ? k_w : (mode == 1) ? v_w : q_w;
    const float sc = (mode == 2) ? 0.0450842200277801f : 1.0f;  // log2(e)/32
    unsigned short* outp = Wfrag + (size_t)mode * 32768;

    const int s  = blockIdx.x * 256 + threadIdx.x;   // (kk,nt,lane) slot
    const int l  = s & 63;
    const int nt = (s >> 6) & 3;
    const int kk = s >> 8;
    const int lr = l & 15, lg = l >> 4;
    short8 frag;
    #pragma unroll
    for (int j = 0; j < 8; ++j)
        frag[j] = (short)f2bf(w[(kk * 32 + lg * 8 + j) * 64 + nt * 16 + lr] * sc);
    *(short8*)&outp[(size_t)s * 8] = frag;
}

// ---------------------------------------------------------------------------
// proj (r5 structure + nt loads). Grid (512, 3), 512 thr = 8 waves.
// Block owns 128 rows x K=512. A staged per 128-col chunk: coalesced
// NON-TEMPORAL fp32 loads, f2bf, ds_write with XOR swizzle. Double buffer.
// ---------------------------------------------------------------------------
__global__ __launch_bounds__(512, 2)
void proj_kernel(const float* __restrict__ k_in, const float* __restrict__ v_in,
                 const float* __restrict__ q_in,
                 const unsigned short* __restrict__ Wfrag,
                 unsigned short* __restrict__ Kb, unsigned short* __restrict__ Vt,
                 unsigned short* __restrict__ Qb)
{
    const int mode = blockIdx.y;
    const float* in = (mode == 0) ? k_in : (mode == 1) ? v_in : q_in;
    const unsigned short* wf = Wfrag + (size_t)mode * 32768;

    __shared__ __align__(16) unsigned short Wlds[32768];       // 64 KB
    __shared__ __align__(16) unsigned short Alds[2][16384];    // 2 x 32 KB

    const int tid = threadIdx.x;
    const int wid = tid >> 6;
    const int l   = tid & 63;
    const int lr  = l & 15;
    const int lg  = l >> 4;
    const int r0  = blockIdx.x * 128;

    const int srow = tid >> 5;
    const int scol = tid & 31;
    const float* sbase = in + (size_t)(r0 + srow) * DIN + scol * 4;

    f32x4 rA[8], rB[8];

    #define LOADC(r, c)                                                        \
        { _Pragma("unroll")                                                    \
          for (int i = 0; i < 8; ++i)                                          \
              r[i] = __builtin_nontemporal_load(                               \
                  (const f32x4*)(sbase + (size_t)i * 16 * DIN + (c) * 128)); }

    #define WRITEC(buf, r)                                                     \
        { _Pragma("unroll")                                                    \
          for (int i = 0; i < 8; ++i) {                                        \
              const int row = srow + i * 16;                                   \
              ushort4 pk;                                                      \
              pk.x = f2bf(r[i].x); pk.y = f2bf(r[i].y);                        \
              pk.z = f2bf(r[i].z); pk.w = f2bf(r[i].w);                        \
              *(ushort4*)((char*)&Alds[buf][0] +                               \
                  ((row * 256 + scol * 8) ^ ((row & 7) << 4))) = pk;           \
          } }

    const int arow  = wid * 16 + lr;
    const int abase = arow * 256 + lg * 16;     // byte offset, + kk*64
    const int aswz  = (arow & 7) << 4;

    f32x4 acc[4];
    #pragma unroll
    for (int nt = 0; nt < 4; ++nt)
        #pragma unroll
        for (int i = 0; i < 4; ++i) acc[nt][i] = 0.f;

    #define COMPUTEC(buf, c)                                                   \
        { _Pragma("unroll")                                                    \
          for (int k = 0; k < 4; ++k) {                                        \
              const short8 af = *(const short8*)((const char*)&Alds[buf][0] +  \
                                  ((abase + k * 64) ^ aswz));                  \
              const int kk = (c) * 4 + k;                                      \
              _Pragma("unroll")                                                \
              for (int nt = 0; nt < 4; ++nt) {                                 \
                  const short8 bf = *(const short8*)&Wlds[((kk * 4 + nt) * 64 + l) * 8]; \
                  acc[nt] = __builtin_amdgcn_mfma_f32_16x16x32_bf16(af, bf, acc[nt], 0, 0, 0); \
              }                                                                \
          } }

    LOADC(rA, 0);
    LOADC(rB, 1);
    #pragma unroll
    for (int i = 0; i < 8; ++i)
        *(short8*)&Wlds[(i * 512 + tid) * 8] = *(const short8*)&wf[(size_t)(i * 512 + tid) * 8];
    WRITEC(0, rA);
    __syncthreads();

    // c=0
    LOADC(rA, 2);
    WRITEC(1, rB);
    COMPUTEC(0, 0);
    __syncthreads();
    // c=1
    LOADC(rB, 3);
    WRITEC(0, rA);
    COMPUTEC(1, 1);
    __syncthreads();
    // c=2
    WRITEC(1, rB);
    COMPUTEC(0, 2);
    __syncthreads();
    // c=3
    COMPUTEC(1, 3);

    if (mode == 1) {
        const int grow = r0 + wid * 16 + lg * 4;
        const int bx = grow >> 10, s = grow & 1023;
        #pragma unroll
        for (int nt = 0; nt < 4; ++nt) {
            ushort4 pk;
            pk.x = f2bf(acc[nt][0]); pk.y = f2bf(acc[nt][1]);
            pk.z = f2bf(acc[nt][2]); pk.w = f2bf(acc[nt][3]);
            *(ushort4*)&Vt[(size_t)bx * 65536 + (size_t)(nt * 16 + lr) * 1024 + s] = pk;
        }
    } else {
        unsigned short* outp = (mode == 0) ? Kb : Qb;
        const int rbase = r0 + wid * 16 + lg * 4;
        #pragma unroll
        for (int nt = 0; nt < 4; ++nt)
            #pragma unroll
            for (int i = 0; i < 4; ++i)
                outp[(size_t)(rbase + i) * 64 + nt * 16 + lr] = f2bf(acc[nt][i]);
    }
    #undef LOADC
    #undef WRITEC
    #undef COMPUTEC
}

// ---------------------------------------------------------------------------
// attn v2. Grid (16, 64), 256 thr = 4 waves; wave owns 16 q-rows.
// Swapped QK^T: t = mfma(K, Q) = S^T -> lane l holds query (qw0 + l&15),
// keys kt*16 + (l>>4)*4 + i. Softmax: in-reg max/sum + 2-step butterfly.
// Log2-domain exp (scale*log2e folded into Q). P packed to LDS (b64 writes).
// PV unchanged: pa rows = queries, acc col=lr->d, row=lg*4+i->query.
// ---------------------------------------------------------------------------
__global__ __launch_bounds__(256)
void attn_kernel(const unsigned short* __restrict__ Qb,
                 const unsigned short* __restrict__ Kb,
                 const unsigned short* __restrict__ Vt,
                 float* __restrict__ out)
{
    __shared__ __align__(16) unsigned short Plds[4][16][72];  // [wave][query][key], padded

    const int tid  = threadIdx.x;
    const int wid  = tid >> 6;
    const int l    = tid & 63;
    const int lr   = l & 15;
    const int lg   = l >> 4;
    const int qblk = 15 - (int)blockIdx.x;       // big blocks first
    const int bx   = blockIdx.y;
    const int qw0  = qblk * 64 + wid * 16;

    const unsigned short* Qp = Qb + (size_t)bx * 65536;
    const unsigned short* Kp = Kb + (size_t)bx * 65536;
    const unsigned short* Vp = Vt + (size_t)bx * 65536;   // [d][s]

    const short8 qa0 = *(const short8*)&Qp[(size_t)(qw0 + lr) * 64 + lg * 8];
    const short8 qa1 = *(const short8*)&Qp[(size_t)(qw0 + lr) * 64 + 32 + lg * 8];

    const int myq = qw0 + lr;        // softmax-side query of this lane
    float m = -INFINITY, lsum = 0.f;

    f32x4 acc[4];
    #pragma unroll
    for (int dt = 0; dt < 4; ++dt)
        #pragma unroll
        for (int i = 0; i < 4; ++i) acc[dt][i] = 0.f;

    for (int kb = 0; kb <= qw0; kb += 64) {
        // ---- scores S^T: 4 tiles of 16 keys ----
        f32x4 s[4];
        __builtin_amdgcn_s_setprio(1);
        #pragma unroll
        for (int kt = 0; kt < 4; ++kt) {
            const int kbase = kb + kt * 16;
            if (kbase <= qw0 + 15) {           // wave-uniform
                const short8 k0 = *(const short8*)&Kp[(size_t)(kbase + lr) * 64 + lg * 8];
                const short8 k1 = *(const short8*)&Kp[(size_t)(kbase + lr) * 64 + 32 + lg * 8];
                f32x4 t;
                #pragma unroll
                for (int i = 0; i < 4; ++i) t[i] = 0.f;
                t = __builtin_amdgcn_mfma_f32_16x16x32_bf16(k0, qa0, t, 0, 0, 0);
                t = __builtin_amdgcn_mfma_f32_16x16x32_bf16(k1, qa1, t, 0, 0, 0);
                #pragma unroll
                for (int i = 0; i < 4; ++i)
                    s[kt][i] = (kbase + lg * 4 + i <= myq) ? t[i] : -INFINITY;
            } else {
                #pragma unroll
                for (int i = 0; i < 4; ++i) s[kt][i] = -INFINITY;
            }
        }
        __builtin_amdgcn_s_setprio(0);

        // ---- V loads for this chunk (latency hides under softmax) ----
        const int cmax = (kb + 32 <= qw0 + 15) ? 2 : 1;
        short8 vb[2][4];
        #pragma unroll
        for (int dt = 0; dt < 4; ++dt)
            vb[0][dt] = *(const short8*)&Vp[(size_t)(dt * 16 + lr) * 1024 + kb + lg * 8];
        if (cmax == 2) {
            #pragma unroll
            for (int dt = 0; dt < 4; ++dt)
                vb[1][dt] = *(const short8*)&Vp[(size_t)(dt * 16 + lr) * 1024 + kb + 32 + lg * 8];
        }

        // ---- softmax (log2 domain), lane-local rows ----
        float tm = s[0][0];
        #pragma unroll
        for (int kt = 0; kt < 4; ++kt)
            #pragma unroll
            for (int i = 0; i < 4; ++i)
                if (kt + i) tm = fmaxf(tm, s[kt][i]);
        tm = fmaxf(tm, __shfl_xor(tm, 16));
        tm = fmaxf(tm, __shfl_xor(tm, 32));

        const float mn = fmaxf(m, tm);
        const float rs = fast_exp2(m - mn);
        m = mn;

        float ps = 0.f;
        float p[4][4];
        #pragma unroll
        for (int kt = 0; kt < 4; ++kt)
            #pragma unroll
            for (int i = 0; i < 4; ++i) {
                p[kt][i] = fast_exp2(s[kt][i] - m);   // masked -> 0
                ps += p[kt][i];
            }
        ps += __shfl_xor(ps, 16);
        ps += __shfl_xor(ps, 32);
        lsum = lsum * rs + ps;

        // ---- write P (4 x ds_write_b64: 4 consecutive keys per lane) ----
        #pragma unroll
        for (int kt = 0; kt < 4; ++kt) {
            ushort4 pk;
            pk.x = f2bf_rhu(p[kt][0]); pk.y = f2bf_rhu(p[kt][1]);
            pk.z = f2bf_rhu(p[kt][2]); pk.w = f2bf_rhu(p[kt][3]);
            *(ushort4*)&Plds[wid][lr][kt * 16 + lg * 4] = pk;
        }

        // ---- rescale acc (PV query layout: row = lg*4 + i) ----
        float rsP[4];
        #pragma unroll
        for (int i = 0; i < 4; ++i)
            rsP[i] = __shfl(rs, (l & 48) | (lg * 4 + i));
        #pragma unroll
        for (int dt = 0; dt < 4; ++dt)
            #pragma unroll
            for (int i = 0; i < 4; ++i) acc[dt][i] *= rsP[i];

        asm volatile("s_waitcnt lgkmcnt(0)" ::: "memory");
        __builtin_amdgcn_sched_barrier(0);

        // ---- PV ----
        __builtin_amdgcn_s_setprio(1);
        for (int c = 0; c < cmax; ++c) {
            const short8 pa = *(const short8*)&Plds[wid][lr][c * 32 + lg * 8];
            #pragma unroll
            for (int dt = 0; dt < 4; ++dt)
                acc[dt] = __builtin_amdgcn_mfma_f32_16x16x32_bf16(pa, vb[c][dt], acc[dt], 0, 0, 0);
        }
        __builtin_amdgcn_s_setprio(0);
        asm volatile("s_waitcnt lgkmcnt(0)" ::: "memory");
    }

    // ---- epilogue ----
    const float invq = 1.0f / lsum;
    float inv[4];
    #pragma unroll
    for (int i = 0; i < 4; ++i)
        inv[i] = __shfl(invq, (l & 48) | (lg * 4 + i));
    const size_t orow = (size_t)bx * 1024 + qw0;
    #pragma unroll
    for (int dt = 0; dt < 4; ++dt)
        #pragma unroll
        for (int i = 0; i < 4; ++i)
            out[(orow + lg * 4 + i) * 64 + dt * 16 + lr] = acc[dt][i] * inv[i];
}

extern "C" void kernel_launch(void* const* d_in, const int* in_sizes, int n_in,
                              void* d_out, int out_size, void* d_ws, size_t ws_size,
                              hipStream_t stream) {
    const float* k_in = (const float*)d_in[0];
    const float* v_in = (const float*)d_in[1];
    const float* q_in = (const float*)d_in[2];
    const float* k_w  = (const float*)d_in[3];
    const float* v_w  = (const float*)d_in[4];
    const float* q_w  = (const float*)d_in[5];

    unsigned short* Kb    = (unsigned short*)d_ws;              // [65536][64] bf16
    unsigned short* Vt    = Kb + (size_t)NROWS * 64;            // [64][64][1024] bf16
    unsigned short* Qb    = Vt + (size_t)NROWS * 64;            // [65536][64] bf16 (scale in W)
    unsigned short* Wfrag = Qb + (size_t)NROWS * 64;            // 3 x 32768 bf16 fragments

    wprep_kernel<<<dim3(16, 3), 256, 0, stream>>>(k_w, v_w, q_w, Wfrag);
    proj_kernel<<<dim3(512, 3), 512, 0, stream>>>(
        k_in, v_in, q_in, Wfrag, Kb, Vt, Qb);
    attn_kernel<<<dim3(16, 64), 256, 0, stream>>>(Qb, Kb, Vt, (float*)d_out);
}